// Round 16
// baseline (772.362 us; speedup 1.0000x reference)
//
#include <hip/hip_runtime.h>

#define LBL 64
#define TT 1024
#define BB 256
#define BOS 62
#define EOS 63
#define NEGV -10000.0f

typedef float v2f __attribute__((ext_vector_type(2)));
typedef float v4f __attribute__((ext_vector_type(4)));

__device__ __forceinline__ float rl_f(float v, int l) {
    return __uint_as_float(__builtin_amdgcn_readlane(__float_as_uint(v), l));
}

// ---------------- forward: VALUE-ONLY serial recurrence ----------------
// One wave per sentence. Per step: LDS-broadcast fv (vq prefetch) + pk_add/
// pk_max tree. No index phase, no bp. Stores the pre-emission max row m
// once per 8 steps (chunk boundary for the bp kernel).
__global__ __launch_bounds__(64, 1) void viterbi_fwd(
    const float* __restrict__ X, const float* __restrict__ trans,
    float* __restrict__ out, float* __restrict__ mS, int* __restrict__ tags)
{
    __shared__ __align__(16) float fvrow[LBL];

    const int lane = threadIdx.x;            // next-label n
    const int b    = blockIdx.x;

    v2f tc2[32];                             // T[2i..2i+1][n] packed
#pragma unroll
    for (int i = 0; i < 32; ++i) {
        tc2[i][0] = trans[(2*i)   * LBL + lane];
        tc2[i][1] = trans[(2*i+1) * LBL + lane];
    }

    const float* Xb  = X  + (size_t)b * TT * LBL + lane;
    float*       mSp = mS + (size_t)b * (TT/8) * LBL + lane;

    float fvv = (lane == BOS) ? 0.0f : NEGV; // fv_{-1}
    fvrow[lane] = fvv;
    v4f vq[16];
#pragma unroll
    for (int g = 0; g < 16; ++g) vq[g] = ((const v4f*)fvrow)[g];

    auto STEP = [&](float e) -> float {
        float vgs[8];
#pragma unroll
        for (int g = 0; g < 8; ++g) {
            const v4f fa = vq[2*g];
            const v4f fb = vq[2*g + 1];
            v2f s0 = __builtin_shufflevector(fa, fa, 0, 1) + tc2[4*g+0];
            v2f s1 = __builtin_shufflevector(fa, fa, 2, 3) + tc2[4*g+1];
            v2f s2 = __builtin_shufflevector(fb, fb, 0, 1) + tc2[4*g+2];
            v2f s3 = __builtin_shufflevector(fb, fb, 2, 3) + tc2[4*g+3];
            v2f w0 = __builtin_elementwise_max(s0, s1);   // v_pk_max_f32
            v2f w1 = __builtin_elementwise_max(s2, s3);
            v2f w  = __builtin_elementwise_max(w0, w1);
            vgs[g] = fmaxf(w[0], w[1]);
        }
        const float m =
            fmaxf(fmaxf(fmaxf(vgs[0], vgs[1]), fmaxf(vgs[2], vgs[3])),
                  fmaxf(fmaxf(vgs[4], vgs[5]), fmaxf(vgs[6], vgs[7])));
        fvv = m + e;                  // exact f32 add == numpy
        fvrow[lane] = fvv;
        __builtin_amdgcn_sched_barrier(0);
        const v4f* fr = (const v4f*)fvrow;   // prefetch next step (DS FIFO)
#pragma unroll
        for (int g = 0; g < 16; ++g) vq[g] = fr[g];
        __builtin_amdgcn_sched_barrier(0);
        return m;
    };

    float eC[8], eN[8];
#pragma unroll
    for (int j = 0; j < 8; ++j) eC[j] = Xb[(size_t)j * LBL];

    for (int base = 0; base < TT; base += 8) {
        if (base + 8 < TT) {                 // uniform branch
#pragma unroll
            for (int j = 0; j < 8; ++j)
                eN[j] = Xb[(size_t)(base + 8 + j) * LBL];
        }
        float mlast = 0.0f;
#pragma unroll
        for (int j = 0; j < 8; ++j) mlast = STEP(eC[j]);
        mSp[(size_t)(base >> 3) * LBL] = mlast;   // chunk-boundary m row
#pragma unroll
        for (int j = 0; j < 8; ++j) eC[j] = eN[j];
    }

    // termination + wave argmax (butterfly, lower index wins ties)
    float bv = fvv + trans[lane * LBL + EOS];
    int   bi = lane;
#pragma unroll
    for (int d = 1; d < 64; d <<= 1) {
        float ov = __shfl_xor(bv, d, 64);
        int   oi = __shfl_xor(bi, d, 64);
        if (ov > bv || (ov == bv && oi < bi)) { bv = ov; bi = oi; }
    }
    if (lane == 0) { out[b] = bv; tags[b] = bi; }
}

// ---------------- bp recompute: massively parallel, no serial chain ----------------
// 32768 independent 8-step chunks (wave = chunk, lane = n). Rebuilds
// fv_{8c-1} = mS[c-1] + X[8c-1] (bitwise-exact), then per step recomputes the
// 64 sums with the same f32 adds, m = order-free max, bp = first p with s==m.
__global__ __launch_bounds__(256, 2) void viterbi_bp(
    const float* __restrict__ X, const float* __restrict__ trans,
    const float* __restrict__ mS, unsigned* __restrict__ bpP)
{
    const int tid   = threadIdx.x;
    const int lane  = tid & 63;              // next-label n
    const int wv    = tid >> 6;
    const int chunk = blockIdx.x * 4 + wv;   // 0..32767
    const int b     = chunk >> 7;
    const int c     = chunk & 127;

    float tc[LBL];
#pragma unroll
    for (int p = 0; p < LBL; ++p) tc[p] = trans[p * LBL + lane];

    float fvp;                               // fv_{8c-1}[lane]
    if (c == 0) fvp = (lane == BOS) ? 0.0f : NEGV;
    else fvp = mS[((size_t)b * (TT/8) + (c-1)) * LBL + lane]
             + X[((size_t)b * TT + (8*c - 1)) * LBL + lane];

    const float* Xb = X + ((size_t)b * TT + 8*c) * LBL + lane;

    unsigned pk0 = 0, pk1 = 0;
#pragma unroll
    for (int j = 0; j < 8; ++j) {
        float e = Xb[(size_t)j * LBL];
        float s[LBL];
#pragma unroll
        for (int p = 0; p < LBL; ++p)
            s[p] = rl_f(fvp, p) + tc[p];     // same IEEE add as forward
        float u[32];
#pragma unroll
        for (int k = 0; k < 32; ++k) u[k] = fmaxf(s[2*k], s[2*k+1]);
#pragma unroll
        for (int st = 8; st >= 1; st >>= 1)
#pragma unroll
            for (int k = 0; k < st; ++k) u[k] = fmaxf(u[2*k], u[2*k+1]);
        const float m = u[0];                // order-free => bitwise == fwd m
        int kk = 63;
#pragma unroll
        for (int p = 62; p >= 0; --p) kk = (s[p] == m) ? p : kk;  // first occ.
        if (j < 4) pk0 |= ((unsigned)kk) << (8*j);
        else       pk1 |= ((unsigned)kk) << (8*(j-4));
        fvp = m + e;                         // exact chain within chunk
    }
    unsigned* bw = bpP + ((size_t)b * (TT/4) + 2*c) * LBL + lane;
    bw[0]   = pk0;                           // t4 = 2c
    bw[LBL] = pk1;                           // t4 = 2c+1
}

// ---------------- backtrack: word-packed chase, 8-word prefetch ----------------
__global__ __launch_bounds__(64, 1) void viterbi_bt(
    const unsigned* __restrict__ bpP, const int* __restrict__ tags,
    float* __restrict__ out)
{
    __shared__ unsigned char path_s[TT];
    const int lane = threadIdx.x;
    const int b    = blockIdx.x;
    const unsigned* bpW = bpP + (size_t)b * (TT/4) * LBL + lane;

    int stag = tags[b];                      // wave-uniform start tag
    unsigned w[8];
#pragma unroll
    for (int i = 0; i < 8; ++i) w[i] = bpW[(size_t)(255 - i) * LBL];

    for (int t4 = 255; t4 >= 0; t4 -= 8) {
        unsigned nw[8];
        const int nbase = t4 - 8;
#pragma unroll
        for (int i = 0; i < 8; ++i) {
            int idx = nbase - i; if (idx < 0) idx = 0;
            nw[i] = bpW[(size_t)idx * LBL];
        }
#pragma unroll
        for (int i = 0; i < 8; ++i) {
            const int tt4 = t4 - i;
            const unsigned ww = w[i];
#pragma unroll
            for (int sub = 3; sub >= 0; --sub) {
                const int t = 4 * tt4 + sub;
                if (lane == (t & 63)) path_s[t] = (unsigned char)stag;
                unsigned wr = (unsigned)__builtin_amdgcn_readlane((int)ww, stag);
                stag = (int)((wr >> (8 * sub)) & 0xFFu);
            }
        }
#pragma unroll
        for (int i = 0; i < 8; ++i) w[i] = nw[i];
    }
    __syncthreads();

    float* po = out + BB + (size_t)b * TT;
#pragma unroll
    for (int i = 0; i < TT / LBL; ++i)
        po[i * LBL + lane] = (float)path_s[i * LBL + lane];
}

extern "C" void kernel_launch(void* const* d_in, const int* in_sizes, int n_in,
                              void* d_out, int out_size, void* d_ws, size_t ws_size,
                              hipStream_t stream)
{
    const float* X     = (const float*)d_in[0];   // [256, 1024, 64]
    const float* trans = (const float*)d_in[1];   // [64, 64]
    float* out = (float*)d_out;                   // [256] scores ++ [256*1024] path

    // ws layout: mS [256][128][64] f32 (8.39 MB) | bpP [256][256][64] u32
    // (16.78 MB) | tags [256] int  => 25.2 MB total
    float*    mS   = (float*)d_ws;
    unsigned* bpP  = (unsigned*)((char*)d_ws + (size_t)BB * (TT/8) * LBL * 4);
    int*      tags = (int*)((char*)d_ws + (size_t)BB * (TT/8) * LBL * 4
                                        + (size_t)BB * (TT/4) * LBL * 4);

    viterbi_fwd<<<dim3(BB),      dim3(64),  0, stream>>>(X, trans, out, mS, tags);
    viterbi_bp <<<dim3(BB*32),   dim3(256), 0, stream>>>(X, trans, mS, bpP);
    viterbi_bt <<<dim3(BB),      dim3(64),  0, stream>>>(bpP, tags, out);
}

// Round 17
// 343.167 us; speedup vs baseline: 2.2507x; 2.2507x over previous
//
#include <hip/hip_runtime.h>

#define LBL 64
#define TT 1024
#define BB 256
#define BOS 62
#define EOS 63
#define NEGV -10000.0f

typedef float v2f __attribute__((ext_vector_type(2)));
typedef float v4f __attribute__((ext_vector_type(4)));

__device__ __forceinline__ float rl_f(float v, int l) {
    return __uint_as_float(__builtin_amdgcn_readlane(__float_as_uint(v), l));
}

// ---------------- forward: VALUE-ONLY serial recurrence (r16, unchanged) ----------------
__global__ __launch_bounds__(64, 1) void viterbi_fwd(
    const float* __restrict__ X, const float* __restrict__ trans,
    float* __restrict__ out, float* __restrict__ mS, int* __restrict__ tags)
{
    __shared__ __align__(16) float fvrow[LBL];

    const int lane = threadIdx.x;            // next-label n
    const int b    = blockIdx.x;

    v2f tc2[32];                             // T[2i..2i+1][n] packed
#pragma unroll
    for (int i = 0; i < 32; ++i) {
        tc2[i][0] = trans[(2*i)   * LBL + lane];
        tc2[i][1] = trans[(2*i+1) * LBL + lane];
    }

    const float* Xb  = X  + (size_t)b * TT * LBL + lane;
    float*       mSp = mS + (size_t)b * (TT/8) * LBL + lane;

    float fvv = (lane == BOS) ? 0.0f : NEGV; // fv_{-1}
    fvrow[lane] = fvv;
    v4f vq[16];
#pragma unroll
    for (int g = 0; g < 16; ++g) vq[g] = ((const v4f*)fvrow)[g];

    auto STEP = [&](float e) -> float {
        float vgs[8];
#pragma unroll
        for (int g = 0; g < 8; ++g) {
            const v4f fa = vq[2*g];
            const v4f fb = vq[2*g + 1];
            v2f s0 = __builtin_shufflevector(fa, fa, 0, 1) + tc2[4*g+0];
            v2f s1 = __builtin_shufflevector(fa, fa, 2, 3) + tc2[4*g+1];
            v2f s2 = __builtin_shufflevector(fb, fb, 0, 1) + tc2[4*g+2];
            v2f s3 = __builtin_shufflevector(fb, fb, 2, 3) + tc2[4*g+3];
            v2f w0 = __builtin_elementwise_max(s0, s1);   // v_pk_max_f32
            v2f w1 = __builtin_elementwise_max(s2, s3);
            v2f w  = __builtin_elementwise_max(w0, w1);
            vgs[g] = fmaxf(w[0], w[1]);
        }
        const float m =
            fmaxf(fmaxf(fmaxf(vgs[0], vgs[1]), fmaxf(vgs[2], vgs[3])),
                  fmaxf(fmaxf(vgs[4], vgs[5]), fmaxf(vgs[6], vgs[7])));
        fvv = m + e;                  // exact f32 add == numpy
        fvrow[lane] = fvv;
        __builtin_amdgcn_sched_barrier(0);
        const v4f* fr = (const v4f*)fvrow;   // prefetch next step (DS FIFO)
#pragma unroll
        for (int g = 0; g < 16; ++g) vq[g] = fr[g];
        __builtin_amdgcn_sched_barrier(0);
        return m;
    };

    float eC[8], eN[8];
#pragma unroll
    for (int j = 0; j < 8; ++j) eC[j] = Xb[(size_t)j * LBL];

    for (int base = 0; base < TT; base += 8) {
        if (base + 8 < TT) {                 // uniform branch
#pragma unroll
            for (int j = 0; j < 8; ++j)
                eN[j] = Xb[(size_t)(base + 8 + j) * LBL];
        }
        float mlast = 0.0f;
#pragma unroll
        for (int j = 0; j < 8; ++j) mlast = STEP(eC[j]);
        mSp[(size_t)(base >> 3) * LBL] = mlast;   // chunk-boundary m row
#pragma unroll
        for (int j = 0; j < 8; ++j) eC[j] = eN[j];
    }

    // termination + wave argmax (butterfly, lower index wins ties)
    float bv = fvv + trans[lane * LBL + EOS];
    int   bi = lane;
#pragma unroll
    for (int d = 1; d < 64; d <<= 1) {
        float ov = __shfl_xor(bv, d, 64);
        int   oi = __shfl_xor(bi, d, 64);
        if (ov > bv || (ov == bv && oi < bi)) { bv = ov; bi = oi; }
    }
    if (lane == 0) { out[b] = bv; tags[b] = bi; }
}

// ---------------- bp recompute: massively parallel (FIXED) ----------------
// Wave = one 8-step chunk, lane = n. Per step: per-group max trees (vg[8],
// no 64-wide array -> no spill, no stride bug), m = max(vg) (set-max, bitwise
// == forward), gs = first group == m, then recompute ONLY group gs's 8 sums
// via __shfl (ds_bpermute, divergent gs ok) + LDS trans gather; first k with
// q==m. Same IEEE adds => exact np.argmax first-occurrence.
__global__ __launch_bounds__(256, 2) void viterbi_bp(
    const float* __restrict__ X, const float* __restrict__ trans,
    const float* __restrict__ mS, unsigned* __restrict__ bpP)
{
    __shared__ __align__(16) float tlds[LBL * LBL];   // [p][n], 16 KiB

    const int tid   = threadIdx.x;
    const int lane  = tid & 63;              // next-label n
    const int wv    = tid >> 6;
    const int chunk = blockIdx.x * 4 + wv;   // 0..32767
    const int b     = chunk >> 7;
    const int c     = chunk & 127;

    float tc[LBL];
#pragma unroll
    for (int p = 0; p < LBL; ++p) tc[p] = trans[p * LBL + lane];
    // cooperative tlds init: wave wv writes rows [16*wv, 16*wv+16)
#pragma unroll
    for (int i = 0; i < 16; ++i)
        tlds[(wv * 16 + i) * LBL + lane] = trans[(wv * 16 + i) * LBL + lane];
    __syncthreads();

    float fvp;                               // fv_{8c-1}[lane]
    if (c == 0) fvp = (lane == BOS) ? 0.0f : NEGV;
    else fvp = mS[((size_t)b * (TT/8) + (c-1)) * LBL + lane]
             + X[((size_t)b * TT + (8*c - 1)) * LBL + lane];

    const float* Xb = X + ((size_t)b * TT + 8*c) * LBL + lane;

    unsigned pk0 = 0, pk1 = 0;
#pragma unroll
    for (int j = 0; j < 8; ++j) {
        float e = Xb[(size_t)j * LBL];

        // per-group maxima (same sums as forward: rl+add, bitwise equal)
        float vg[8];
#pragma unroll
        for (int g = 0; g < 8; ++g) {
            float s0 = rl_f(fvp, 8*g+0) + tc[8*g+0];
            float s1 = rl_f(fvp, 8*g+1) + tc[8*g+1];
            float s2 = rl_f(fvp, 8*g+2) + tc[8*g+2];
            float s3 = rl_f(fvp, 8*g+3) + tc[8*g+3];
            float s4 = rl_f(fvp, 8*g+4) + tc[8*g+4];
            float s5 = rl_f(fvp, 8*g+5) + tc[8*g+5];
            float s6 = rl_f(fvp, 8*g+6) + tc[8*g+6];
            float s7 = rl_f(fvp, 8*g+7) + tc[8*g+7];
            vg[g] = fmaxf(fmaxf(fmaxf(s0, s1), fmaxf(s2, s3)),
                          fmaxf(fmaxf(s4, s5), fmaxf(s6, s7)));
        }
        const float m = fmaxf(fmaxf(fmaxf(vg[0], vg[1]), fmaxf(vg[2], vg[3])),
                              fmaxf(fmaxf(vg[4], vg[5]), fmaxf(vg[6], vg[7])));

        // first group containing m
        int gs = 7;
#pragma unroll
        for (int g = 6; g >= 0; --g) gs = (vg[g] == m) ? g : gs;
        const int pbase = gs << 3;

        // recompute group gs's 8 sums: fv via ds_bpermute (divergent index),
        // T via LDS gather (addr = (pbase+k)*256B + lane*4: 2/bank = free)
        const float* tg = &tlds[pbase * LBL + lane];
        float q0 = __shfl(fvp, pbase + 0, 64) + tg[0 * LBL];
        float q1 = __shfl(fvp, pbase + 1, 64) + tg[1 * LBL];
        float q2 = __shfl(fvp, pbase + 2, 64) + tg[2 * LBL];
        float q3 = __shfl(fvp, pbase + 3, 64) + tg[3 * LBL];
        float q4 = __shfl(fvp, pbase + 4, 64) + tg[4 * LBL];
        float q5 = __shfl(fvp, pbase + 5, 64) + tg[5 * LBL];
        float q6 = __shfl(fvp, pbase + 6, 64) + tg[6 * LBL];
        float q7 = __shfl(fvp, pbase + 7, 64) + tg[7 * LBL];
        int k = 7;
        k = (q6 == m) ? 6 : k;
        k = (q5 == m) ? 5 : k;
        k = (q4 == m) ? 4 : k;
        k = (q3 == m) ? 3 : k;
        k = (q2 == m) ? 2 : k;
        k = (q1 == m) ? 1 : k;
        k = (q0 == m) ? 0 : k;               // lowest k = first occurrence
        const unsigned kk = (unsigned)(pbase | k);

        if (j < 4) pk0 |= kk << (8*j);
        else       pk1 |= kk << (8*(j-4));
        fvp = m + e;                         // exact chain within chunk
    }
    unsigned* bw = bpP + ((size_t)b * (TT/4) + 2*c) * LBL + lane;
    bw[0]   = pk0;                           // t4 = 2c   (steps 8c..8c+3)
    bw[LBL] = pk1;                           // t4 = 2c+1 (steps 8c+4..8c+7)
}

// ---------------- backtrack: word-packed chase (r16, unchanged) ----------------
__global__ __launch_bounds__(64, 1) void viterbi_bt(
    const unsigned* __restrict__ bpP, const int* __restrict__ tags,
    float* __restrict__ out)
{
    __shared__ unsigned char path_s[TT];
    const int lane = threadIdx.x;
    const int b    = blockIdx.x;
    const unsigned* bpW = bpP + (size_t)b * (TT/4) * LBL + lane;

    int stag = tags[b];                      // wave-uniform start tag
    unsigned w[8];
#pragma unroll
    for (int i = 0; i < 8; ++i) w[i] = bpW[(size_t)(255 - i) * LBL];

    for (int t4 = 255; t4 >= 0; t4 -= 8) {
        unsigned nw[8];
        const int nbase = t4 - 8;
#pragma unroll
        for (int i = 0; i < 8; ++i) {
            int idx = nbase - i; if (idx < 0) idx = 0;
            nw[i] = bpW[(size_t)idx * LBL];
        }
#pragma unroll
        for (int i = 0; i < 8; ++i) {
            const int tt4 = t4 - i;
            const unsigned ww = w[i];
#pragma unroll
            for (int sub = 3; sub >= 0; --sub) {
                const int t = 4 * tt4 + sub;
                if (lane == (t & 63)) path_s[t] = (unsigned char)stag;
                unsigned wr = (unsigned)__builtin_amdgcn_readlane((int)ww, stag);
                stag = (int)((wr >> (8 * sub)) & 0xFFu);
            }
        }
#pragma unroll
        for (int i = 0; i < 8; ++i) w[i] = nw[i];
    }
    __syncthreads();

    float* po = out + BB + (size_t)b * TT;
#pragma unroll
    for (int i = 0; i < TT / LBL; ++i)
        po[i * LBL + lane] = (float)path_s[i * LBL + lane];
}

extern "C" void kernel_launch(void* const* d_in, const int* in_sizes, int n_in,
                              void* d_out, int out_size, void* d_ws, size_t ws_size,
                              hipStream_t stream)
{
    const float* X     = (const float*)d_in[0];   // [256, 1024, 64]
    const float* trans = (const float*)d_in[1];   // [64, 64]
    float* out = (float*)d_out;                   // [256] scores ++ [256*1024] path

    // ws layout: mS [256][128][64] f32 (8.39 MB) | bpP [256][256][64] u32
    // (16.78 MB) | tags [256] int  => 25.2 MB total
    float*    mS   = (float*)d_ws;
    unsigned* bpP  = (unsigned*)((char*)d_ws + (size_t)BB * (TT/8) * LBL * 4);
    int*      tags = (int*)((char*)d_ws + (size_t)BB * (TT/8) * LBL * 4
                                        + (size_t)BB * (TT/4) * LBL * 4);

    viterbi_fwd<<<dim3(BB),      dim3(64),  0, stream>>>(X, trans, out, mS, tags);
    viterbi_bp <<<dim3(BB*32),   dim3(256), 0, stream>>>(X, trans, mS, bpP);
    viterbi_bt <<<dim3(BB),      dim3(64),  0, stream>>>(bpP, tags, out);
}

// Round 18
// 290.059 us; speedup vs baseline: 2.6628x; 1.1831x over previous
//
#include <hip/hip_runtime.h>

#define LBL 64
#define TT 1024
#define BB 256
#define BOS 62
#define EOS 63
#define NEGV -10000.0f

typedef float v2f __attribute__((ext_vector_type(2)));
typedef float v4f __attribute__((ext_vector_type(4)));

__device__ __forceinline__ float rl_f(float v, int l) {
    return __uint_as_float(__builtin_amdgcn_readlane(__float_as_uint(v), l));
}
__device__ __forceinline__ int acq(int* p) {
    return __hip_atomic_load(p, __ATOMIC_ACQUIRE, __HIP_MEMORY_SCOPE_WORKGROUP);
}
__device__ __forceinline__ void rel(int* p, int v) {
    __hip_atomic_store(p, v, __ATOMIC_RELEASE, __HIP_MEMORY_SCOPE_WORKGROUP);
}

// FUSED: one block per sentence, 4 waves.
//   wave 0  = serial value-only forward (r16-proven, 230us) + bt at the end
//   waves 1-3 = r17-proven bp recompute, consuming windows via LDS ticket
//     (lag <=1 window behind the producer; finish with it; all bp in LDS)
// Producer never waits on consumers; consumers wait only on the monotone
// ticket -> deadlock-free. Consumers run on other SIMDs: no issue contention.
__global__ __launch_bounds__(256, 1) void viterbi_fused(
    const float* __restrict__ X, const float* __restrict__ trans,
    float* __restrict__ out)
{
    __shared__ float msml[TT/8][LBL];                // 32 KiB boundary m rows
    __shared__ unsigned bpw[TT/4][LBL];              // 64 KiB packed bp words
    __shared__ __align__(16) float tlds[LBL * LBL];  // 16 KiB [p][n]
    __shared__ __align__(16) float fvrow[LBL];       // producer broadcast row
    __shared__ unsigned char path_s[TT];
    __shared__ int ticket;

    const int tid  = threadIdx.x;
    const int lane = tid & 63;                  // label index n
    const int wv   = __builtin_amdgcn_readfirstlane(tid >> 6);
    const int b    = blockIdx.x;

    // cooperative tlds init (wave wv writes rows [16wv,16wv+16))
#pragma unroll
    for (int i = 0; i < 16; ++i)
        tlds[(wv * 16 + i) * LBL + lane] = trans[(wv * 16 + i) * LBL + lane];
    if (tid == 0) ticket = 0;
    __syncthreads();

    int bi = 0;                                 // wave 0 terminal tag

    if (wv == 0) {
        // ---------------- producer: value-only serial forward ----------------
        v2f tc2[32];                            // T[2i..2i+1][n] packed
#pragma unroll
        for (int i = 0; i < 32; ++i) {
            tc2[i][0] = trans[(2*i)   * LBL + lane];
            tc2[i][1] = trans[(2*i+1) * LBL + lane];
        }
        const float* Xb = X + (size_t)b * TT * LBL + lane;

        float fvv = (lane == BOS) ? 0.0f : NEGV;
        fvrow[lane] = fvv;
        v4f vq[16];
#pragma unroll
        for (int g = 0; g < 16; ++g) vq[g] = ((const v4f*)fvrow)[g];

        auto STEP = [&](float e) -> float {
            float vgs[8];
#pragma unroll
            for (int g = 0; g < 8; ++g) {
                const v4f fa = vq[2*g];
                const v4f fb = vq[2*g + 1];
                v2f s0 = __builtin_shufflevector(fa, fa, 0, 1) + tc2[4*g+0];
                v2f s1 = __builtin_shufflevector(fa, fa, 2, 3) + tc2[4*g+1];
                v2f s2 = __builtin_shufflevector(fb, fb, 0, 1) + tc2[4*g+2];
                v2f s3 = __builtin_shufflevector(fb, fb, 2, 3) + tc2[4*g+3];
                v2f w0 = __builtin_elementwise_max(s0, s1);   // v_pk_max_f32
                v2f w1 = __builtin_elementwise_max(s2, s3);
                v2f w  = __builtin_elementwise_max(w0, w1);
                vgs[g] = fmaxf(w[0], w[1]);
            }
            const float m =
                fmaxf(fmaxf(fmaxf(vgs[0], vgs[1]), fmaxf(vgs[2], vgs[3])),
                      fmaxf(fmaxf(vgs[4], vgs[5]), fmaxf(vgs[6], vgs[7])));
            fvv = m + e;                  // exact f32 add == numpy
            fvrow[lane] = fvv;
            __builtin_amdgcn_sched_barrier(0);
            const v4f* fr = (const v4f*)fvrow;   // prefetch next step (DS FIFO)
#pragma unroll
            for (int g = 0; g < 16; ++g) vq[g] = fr[g];
            __builtin_amdgcn_sched_barrier(0);
            return m;
        };

        float eC[8], eN[8];
#pragma unroll
        for (int j = 0; j < 8; ++j) eC[j] = Xb[(size_t)j * LBL];

        for (int base = 0; base < TT; base += 8) {
            if (base + 8 < TT) {                 // uniform branch
#pragma unroll
                for (int j = 0; j < 8; ++j)
                    eN[j] = Xb[(size_t)(base + 8 + j) * LBL];
            }
            float mlast = 0.0f;
#pragma unroll
            for (int j = 0; j < 8; ++j) mlast = STEP(eC[j]);
            const int g = base >> 3;
            msml[g][lane] = mlast;               // boundary m row -> LDS
            rel(&ticket, g + 1);                 // publish window g done
#pragma unroll
            for (int j = 0; j < 8; ++j) eC[j] = eN[j];
        }

        // termination + wave argmax (butterfly, lower index wins ties)
        float bv = fvv + trans[lane * LBL + EOS];
        bi = lane;
#pragma unroll
        for (int d = 1; d < 64; d <<= 1) {
            float ov = __shfl_xor(bv, d, 64);
            int   oi = __shfl_xor(bi, d, 64);
            if (ov > bv || (ov == bv && oi < bi)) { bv = ov; bi = oi; }
        }
        if (lane == 0) out[b] = bv;
    } else {
        // ---------------- consumers: bp recompute (r17-proven) ----------------
        float tc[LBL];
#pragma unroll
        for (int p = 0; p < LBL; ++p) tc[p] = tlds[p * LBL + lane];

        const int cw = wv - 1;
        for (int c = cw; c < TT/8; c += 3) {
            if (c > 0) while (acq(&ticket) < c) __builtin_amdgcn_s_sleep(2);

            float fvp;                           // fv_{8c-1}[lane]
            if (c == 0) fvp = (lane == BOS) ? 0.0f : NEGV;
            else fvp = msml[c-1][lane]
                     + X[((size_t)b * TT + (8*c - 1)) * LBL + lane];

            const float* Xb = X + ((size_t)b * TT + 8*c) * LBL + lane;

            unsigned pk0 = 0, pk1 = 0;
#pragma unroll
            for (int j = 0; j < 8; ++j) {
                float e = Xb[(size_t)j * LBL];
                float vg[8];
#pragma unroll
                for (int g = 0; g < 8; ++g) {
                    float s0 = rl_f(fvp, 8*g+0) + tc[8*g+0];
                    float s1 = rl_f(fvp, 8*g+1) + tc[8*g+1];
                    float s2 = rl_f(fvp, 8*g+2) + tc[8*g+2];
                    float s3 = rl_f(fvp, 8*g+3) + tc[8*g+3];
                    float s4 = rl_f(fvp, 8*g+4) + tc[8*g+4];
                    float s5 = rl_f(fvp, 8*g+5) + tc[8*g+5];
                    float s6 = rl_f(fvp, 8*g+6) + tc[8*g+6];
                    float s7 = rl_f(fvp, 8*g+7) + tc[8*g+7];
                    vg[g] = fmaxf(fmaxf(fmaxf(s0, s1), fmaxf(s2, s3)),
                                  fmaxf(fmaxf(s4, s5), fmaxf(s6, s7)));
                }
                const float m = fmaxf(
                    fmaxf(fmaxf(vg[0], vg[1]), fmaxf(vg[2], vg[3])),
                    fmaxf(fmaxf(vg[4], vg[5]), fmaxf(vg[6], vg[7])));

                int gs = 7;                      // first group containing m
#pragma unroll
                for (int g = 6; g >= 0; --g) gs = (vg[g] == m) ? g : gs;
                const int pbase = gs << 3;

                // recompute group gs's 8 sums (same IEEE adds -> bitwise ==)
                const float* tg = &tlds[pbase * LBL + lane];
                float q0 = __shfl(fvp, pbase + 0, 64) + tg[0 * LBL];
                float q1 = __shfl(fvp, pbase + 1, 64) + tg[1 * LBL];
                float q2 = __shfl(fvp, pbase + 2, 64) + tg[2 * LBL];
                float q3 = __shfl(fvp, pbase + 3, 64) + tg[3 * LBL];
                float q4 = __shfl(fvp, pbase + 4, 64) + tg[4 * LBL];
                float q5 = __shfl(fvp, pbase + 5, 64) + tg[5 * LBL];
                float q6 = __shfl(fvp, pbase + 6, 64) + tg[6 * LBL];
                float q7 = __shfl(fvp, pbase + 7, 64) + tg[7 * LBL];
                int k = 7;
                k = (q6 == m) ? 6 : k;
                k = (q5 == m) ? 5 : k;
                k = (q4 == m) ? 4 : k;
                k = (q3 == m) ? 3 : k;
                k = (q2 == m) ? 2 : k;
                k = (q1 == m) ? 1 : k;
                k = (q0 == m) ? 0 : k;           // lowest k = first occurrence
                const unsigned kk = (unsigned)(pbase | k);

                if (j < 4) pk0 |= kk << (8*j);
                else       pk1 |= kk << (8*(j-4));
                fvp = m + e;                     // exact chain within chunk
            }
            bpw[2*c][lane]     = pk0;            // steps 8c..8c+3
            bpw[2*c + 1][lane] = pk1;            // steps 8c+4..8c+7
        }
    }

    __syncthreads();   // all bp words visible; producer done

    if (wv == 0) {
        // ---------------- backtrack from LDS (readlane chase) ----------------
        int stag = bi;                           // uniform (butterfly converged)
        unsigned w[8];
#pragma unroll
        for (int i = 0; i < 8; ++i) w[i] = bpw[255 - i][lane];

        for (int t4 = 255; t4 >= 0; t4 -= 8) {
            unsigned nw[8];
            const int nbase = t4 - 8;
#pragma unroll
            for (int i = 0; i < 8; ++i) {
                int idx = nbase - i; if (idx < 0) idx = 0;
                nw[i] = bpw[idx][lane];
            }
#pragma unroll
            for (int i = 0; i < 8; ++i) {
                const int tt4 = t4 - i;
                const unsigned ww = w[i];
#pragma unroll
                for (int sub = 3; sub >= 0; --sub) {
                    const int t = 4 * tt4 + sub;
                    if (lane == (t & 63)) path_s[t] = (unsigned char)stag;
                    unsigned wr = (unsigned)__builtin_amdgcn_readlane((int)ww, stag);
                    stag = (int)((wr >> (8 * sub)) & 0xFFu);
                }
            }
#pragma unroll
            for (int i = 0; i < 8; ++i) w[i] = nw[i];
        }
    }
    __syncthreads();

    // cooperative float path write (all 256 threads)
    float* po = out + BB + (size_t)b * TT;
#pragma unroll
    for (int i = 0; i < TT / 256; ++i)
        po[i * 256 + tid] = (float)path_s[i * 256 + tid];
}

extern "C" void kernel_launch(void* const* d_in, const int* in_sizes, int n_in,
                              void* d_out, int out_size, void* d_ws, size_t ws_size,
                              hipStream_t stream)
{
    const float* X     = (const float*)d_in[0];   // [256, 1024, 64]
    const float* trans = (const float*)d_in[1];   // [64, 64]
    float* out = (float*)d_out;                   // [256] scores ++ [256*1024] path

    viterbi_fused<<<dim3(BB), dim3(256), 0, stream>>>(X, trans, out);
}